// Round 7
// baseline (108.522 us; speedup 1.0000x reference)
//
#include <hip/hip_runtime.h>
#include <hip/hip_bf16.h>
#include <stdint.h>

// C[4096,10532] = inputs[4096,256] @ concat(lut,queue)[10532,256]^T  (fp32 out)
// R7: ZERO-LDS, ZERO-BARRIER register GEMM. Each wave computes its 64x64
//     quadrant with A/B fragments loaded straight from global (L2/L3-hot,
//     64B-sector-aligned). Fully-unrolled K loop lets the compiler hoist
//     loads arbitrarily far ahead (software pipelining without vmcnt games).
//     Decisive A/B vs the 4 staged variants (all ~57-60us gemm): isolates
//     barrier/staging serialization from the memory wall.

#define M_DIM 4096
#define K_DIM 256
#define N_LUT 5532
#define N_Q   5000
#define N_DIM (N_LUT + N_Q)   // 10532
#define NT_M  32              // 4096/128
#define NT_N  83              // ceil(10532/128)
#define N_PAD (NT_N * 128)    // 10624

typedef _Float16 f16x8 __attribute__((ext_vector_type(8)));
typedef float f32x4 __attribute__((ext_vector_type(4)));

__device__ __forceinline__ unsigned short f2h(float f) {
  union { _Float16 h; unsigned short u; } v;
  v.h = (_Float16)f;   // v_cvt_f16_f32, RNE
  return v.u;
}

// ---------------- convert fp32 -> f16 into workspace ----------------
__global__ __launch_bounds__(256) void convert_kernel(
    const float* __restrict__ inp, const float* __restrict__ lut,
    const float* __restrict__ que, unsigned short* __restrict__ Abf,
    unsigned short* __restrict__ Bbf) {
  const int AV = M_DIM * K_DIM / 4;  // 262144 float4s for A
  int i = blockIdx.x * 256 + threadIdx.x;  // grid sized exactly
  float4 x;
  unsigned short* dst;
  if (i < AV) {
    x = ((const float4*)inp)[i];
    dst = Abf + i * 4;
  } else {
    int e = (i - AV) * 4;          // element index in padded B
    int row = e >> 8;              // /256
    int col = e & 255;
    if (row < N_LUT)
      x = *(const float4*)(lut + (size_t)row * K_DIM + col);
    else if (row < N_DIM)
      x = *(const float4*)(que + (size_t)(row - N_LUT) * K_DIM + col);
    else
      x = make_float4(0.f, 0.f, 0.f, 0.f);
    dst = Bbf + e;
  }
  ushort4 o;
  o.x = f2h(x.x); o.y = f2h(x.y); o.z = f2h(x.z); o.w = f2h(x.w);
  *(ushort4*)dst = o;
}

// ---------------- GEMM: C = A * B^T, both [rows][K] f16, no LDS ----------------
__global__ __launch_bounds__(256, 3) void gemm_kernel(
    const unsigned short* __restrict__ A, const unsigned short* __restrict__ B,
    float* __restrict__ C) {
  const int t = threadIdx.x;
  const int lane = t & 63;
  const int wave = t >> 6;         // 4 waves
  const int wm = wave >> 1;        // 2x2 wave grid, each 64x64 output
  const int wn = wave & 1;

  // XCD chunking (nwg = 2656 = 8 * 332), bn-fast within each chunk
  const int nwg = NT_M * NT_N;
  const int cpx = nwg >> 3;        // 332
  int bid = blockIdx.x;
  int wg = (bid & 7) * cpx + (bid >> 3);
  const int bn = wg % NT_N;        // col-fast: col-neighbors concurrent
  const int bm = wg / NT_N;
  const int brow = bm * 128;
  const int bcol = bn * 128;

  const int lr = lane & 15;
  const int kq = (lane >> 4) * 8;  // this lane's k-slice base (elements)

  // Fragment byte offsets (32-bit; A=2MB, B=5.4MB both fit).
  // a[i]: A-matrix row brow+wm*64+i*16+lr, k = ks*32 + kq  (16B chunk)
  // b[j]: B-matrix row bcol+wn*64+j*16+lr, same k-slice
  const char* __restrict__ Ab = (const char*)A;
  const char* __restrict__ Bb = (const char*)B;
  uint32_t aoff[4], boff[4];
#pragma unroll
  for (int i = 0; i < 4; ++i)
    aoff[i] = (uint32_t)((brow + wm * 64 + i * 16 + lr) * K_DIM + kq) * 2u;
#pragma unroll
  for (int j = 0; j < 4; ++j)
    boff[j] = (uint32_t)((bcol + wn * 64 + j * 16 + lr) * K_DIM + kq) * 2u;

  f32x4 acc[4][4] = {};

  // K = 256 = 8 steps of 32. Fully unrolled: 64 dwordx4 loads + 128 MFMAs,
  // no barriers -> compiler hoists loads ahead of dependent MFMAs freely.
#pragma unroll
  for (int ks = 0; ks < 8; ++ks) {
    f16x8 a[4], b[4];
#pragma unroll
    for (int i = 0; i < 4; ++i)
      a[i] = *(const f16x8*)(Ab + (aoff[i] + ks * 64));
#pragma unroll
    for (int j = 0; j < 4; ++j)
      b[j] = *(const f16x8*)(Bb + (boff[j] + ks * 64));
    // swapped operands (verified R6): row = i*16+lr, cols = j*16 + (lane>>4)*4
#pragma unroll
    for (int i = 0; i < 4; ++i)
#pragma unroll
      for (int j = 0; j < 4; ++j)
        acc[i][j] = __builtin_amdgcn_mfma_f32_16x16x32_f16(b[j], a[i],
                                                           acc[i][j], 0, 0, 0);
  }

  // epilogue (verified R6): lane holds 4 consecutive C-cols -> dwordx4 stores
  const int cc4 = (lane >> 4) * 4;
#pragma unroll
  for (int i = 0; i < 4; ++i) {
    size_t rowBase = (size_t)(brow + wm * 64 + i * 16 + lr) * N_DIM;
#pragma unroll
    for (int j = 0; j < 4; ++j) {
      int col = bcol + wn * 64 + j * 16 + cc4;
      if (col < N_DIM)
        *(f32x4*)&C[rowBase + col] = acc[i][j];
    }
  }
}

extern "C" void kernel_launch(void* const* d_in, const int* in_sizes, int n_in,
                              void* d_out, int out_size, void* d_ws, size_t ws_size,
                              hipStream_t stream) {
  const float* inp = (const float*)d_in[0];   // inputs [4096,256]
  // d_in[1] targets, d_in[2] gt_flag: unused by the forward similarity
  const float* lut = (const float*)d_in[3];   // [5532,256]
  const float* que = (const float*)d_in[4];   // [5000,256]
  float* C = (float*)d_out;                   // [4096,10532]

  unsigned short* Abf = (unsigned short*)d_ws;
  unsigned short* Bbf = Abf + (size_t)M_DIM * K_DIM;  // ~7.6 MB of ws

  const int conv_blocks = (M_DIM * K_DIM / 4 + N_PAD * K_DIM / 4) / 256;
  convert_kernel<<<conv_blocks, 256, 0, stream>>>(inp, lut, que, Abf, Bbf);

  gemm_kernel<<<NT_M * NT_N, 256, 0, stream>>>(Abf, Bbf, C);
}

// Round 8
// 65.595 us; speedup vs baseline: 1.6544x; 1.6544x over previous
//
#include <hip/hip_runtime.h>
#include <hip/hip_bf16.h>
#include <stdint.h>

// C[4096,10532] = inputs[4096,256] @ concat(lut,queue)[10532,256]^T  (fp32 out)
// R8 = R6 structure (single-buffer LDS, __syncthreads 2-phase, swizzled
// staging, bn-fast XCD order, swapped-operand MFMA + dwordx4 stores) with
// OCCUPANCY raised 2 -> 4 blocks/CU:
//   - __launch_bounds__(256, 4): unified VGPR cap 128/wave
//   - inner loop streams A fragments one at a time (64 acc + 16 b + 2 a
//     ~= 100 regs) so the cap holds without scratch spills
// Rationale: R7's clean profile showed stores NOT amplified (WRITE=175MB),
// MFMA work only ~9us; the staged kernels' ~57us is serialization at 8
// waves/CU (152 unified regs -> 2 waves/SIMD). 4 resident blocks let
// stage-drain and store-backpressure phases interleave across blocks.

#define M_DIM 4096
#define K_DIM 256
#define N_LUT 5532
#define N_Q   5000
#define N_DIM (N_LUT + N_Q)   // 10532
#define NT_M  32              // 4096/128
#define NT_N  83              // ceil(10532/128)
#define N_PAD (NT_N * 128)    // 10624

typedef _Float16 f16x8 __attribute__((ext_vector_type(8)));
typedef float f32x4 __attribute__((ext_vector_type(4)));

__device__ __forceinline__ unsigned short f2h(float f) {
  union { _Float16 h; unsigned short u; } v;
  v.h = (_Float16)f;   // v_cvt_f16_f32, RNE
  return v.u;
}

// ---------------- convert fp32 -> f16 into workspace ----------------
__global__ __launch_bounds__(256) void convert_kernel(
    const float* __restrict__ inp, const float* __restrict__ lut,
    const float* __restrict__ que, unsigned short* __restrict__ Abf,
    unsigned short* __restrict__ Bbf) {
  const int AV = M_DIM * K_DIM / 4;  // 262144 float4s for A
  int i = blockIdx.x * 256 + threadIdx.x;  // grid sized exactly
  float4 x;
  unsigned short* dst;
  if (i < AV) {
    x = ((const float4*)inp)[i];
    dst = Abf + i * 4;
  } else {
    int e = (i - AV) * 4;          // element index in padded B
    int row = e >> 8;              // /256
    int col = e & 255;
    if (row < N_LUT)
      x = *(const float4*)(lut + (size_t)row * K_DIM + col);
    else if (row < N_DIM)
      x = *(const float4*)(que + (size_t)(row - N_LUT) * K_DIM + col);
    else
      x = make_float4(0.f, 0.f, 0.f, 0.f);
    dst = Bbf + e;
  }
  ushort4 o;
  o.x = f2h(x.x); o.y = f2h(x.y); o.z = f2h(x.z); o.w = f2h(x.w);
  *(ushort4*)dst = o;
}

// ---------------- GEMM: C = A * B^T, both [rows][K] f16 ----------------
#define GLDS16(gsrc, ldst)                                                  \
  __builtin_amdgcn_global_load_lds(                                         \
      (__attribute__((address_space(1))) void*)(gsrc),                      \
      (__attribute__((address_space(3))) void*)(ldst), 16, 0, 0)

__global__ __launch_bounds__(256, 4) void gemm_kernel(
    const unsigned short* __restrict__ A, const unsigned short* __restrict__ B,
    float* __restrict__ C) {
  // single-buffered 128x64 f16 tiles: 32 KB total -> 4 blocks/CU (128KB LDS)
  __shared__ __align__(16) unsigned short As[128 * 64];
  __shared__ __align__(16) unsigned short Bs[128 * 64];

  const int t = threadIdx.x;
  const int lane = t & 63;
  const int wave = t >> 6;         // 4 waves
  const int wm = wave >> 1;        // 2x2 wave grid, each 64x64 output
  const int wn = wave & 1;

  // XCD chunking (nwg = 2656 = 8 * 332), bn-fast within each chunk
  const int nwg = NT_M * NT_N;
  const int cpx = nwg >> 3;        // 332
  int bid = blockIdx.x;
  int wg = (bid & 7) * cpx + (bid >> 3);
  const int bn = wg % NT_N;        // col-fast: col-neighbors concurrent
  const int bm = wg / NT_N;
  const int brow = bm * 128;
  const int bcol = bn * 128;

  // ---- staging with PRE-SWIZZLED global source (LDS dest stays linear) ----
  // lds[row][ch] = global[row][ch ^ (row&7)]  (16B chunks)
  const int trow = t >> 3;                       // 0..31
  const int tcs = (((t & 7) ^ (trow & 7)) * 8);  // swizzled col, elements
  const unsigned short* gaBase = A + (size_t)(brow + trow) * K_DIM + tcs;
  const unsigned short* gbBase = B + (size_t)(bcol + trow) * K_DIM + tcs;
  const int ldsOff = wave * 512;   // elements; HW adds lane*16 bytes

#define STAGE(kt)                                                            \
  do {                                                                       \
    _Pragma("unroll") for (int is = 0; is < 4; ++is) {                       \
      GLDS16(gaBase + (size_t)is * 32 * K_DIM + (kt) * 64,                   \
             As + is * 2048 + ldsOff);                                       \
      GLDS16(gbBase + (size_t)is * 32 * K_DIM + (kt) * 64,                   \
             Bs + is * 2048 + ldsOff);                                       \
    }                                                                        \
  } while (0)

  f32x4 acc[4][4] = {};
  const int lr = lane & 15;
  const int rsw = lane & 7;        // = row&7 for all fragment rows
  const int cq = lane >> 4;        // quarter-wave id = base col chunk

#pragma unroll
  for (int kt = 0; kt < 4; ++kt) { // K = 256 = 4 * 64
    STAGE(kt);
    __syncthreads();               // vmcnt(0)+lgkmcnt(0) drain + barrier

#pragma unroll
    for (int kk = 0; kk < 64; kk += 32) {
      // desired 16B chunk c = kk/8 + cq; read swizzled chunk c ^ (row&7)
      const int ch = ((kk >> 3) + cq) ^ rsw;   // 0..7
      // hold only B fragments (16 regs); stream A one fragment at a time
      f16x8 b[4];
#pragma unroll
      for (int j = 0; j < 4; ++j)
        b[j] = *(const f16x8*)&Bs[(wn * 64 + j * 16 + lr) * 64 + ch * 8];
#pragma unroll
      for (int i = 0; i < 4; ++i) {
        f16x8 a = *(const f16x8*)&As[(wm * 64 + i * 16 + lr) * 64 + ch * 8];
        // swapped operands: C-row = i*16+lr, C-cols = j*16 + (lane>>4)*4+reg
#pragma unroll
        for (int j = 0; j < 4; ++j)
          acc[i][j] = __builtin_amdgcn_mfma_f32_16x16x32_f16(b[j], a,
                                                             acc[i][j], 0, 0, 0);
      }
    }
    __syncthreads();               // all waves done reading before next STAGE
  }

  // epilogue: lane holds 4 consecutive C-cols -> dwordx4 stores
  const int cc4 = cq * 4;
#pragma unroll
  for (int i = 0; i < 4; ++i) {
    size_t rowBase = (size_t)(brow + wm * 64 + i * 16 + lr) * N_DIM;
#pragma unroll
    for (int j = 0; j < 4; ++j) {
      int col = bcol + wn * 64 + j * 16 + cc4;
      if (col < N_DIM)
        *(f32x4*)&C[rowBase + col] = acc[i][j];
    }
  }
#undef STAGE
}

extern "C" void kernel_launch(void* const* d_in, const int* in_sizes, int n_in,
                              void* d_out, int out_size, void* d_ws, size_t ws_size,
                              hipStream_t stream) {
  const float* inp = (const float*)d_in[0];   // inputs [4096,256]
  // d_in[1] targets, d_in[2] gt_flag: unused by the forward similarity
  const float* lut = (const float*)d_in[3];   // [5532,256]
  const float* que = (const float*)d_in[4];   // [5000,256]
  float* C = (float*)d_out;                   // [4096,10532]

  unsigned short* Abf = (unsigned short*)d_ws;
  unsigned short* Bbf = Abf + (size_t)M_DIM * K_DIM;  // ~7.6 MB of ws

  const int conv_blocks = (M_DIM * K_DIM / 4 + N_PAD * K_DIM / 4) / 256;
  convert_kernel<<<conv_blocks, 256, 0, stream>>>(inp, lut, que, Abf, Bbf);

  gemm_kernel<<<NT_M * NT_N, 256, 0, stream>>>(Abf, Bbf, C);
}